// Round 5
// baseline (714.530 us; speedup 1.0000x reference)
//
#include <hip/hip_runtime.h>
#include <cstdint>
#include <cstddef>

#define NN 50000
#define EE 800000
#define CAP 64
#define EPS_BN 1e-5f

typedef short  s16x8 __attribute__((ext_vector_type(8)));
typedef float  f32x4 __attribute__((ext_vector_type(4)));

#define MFMA16(a, b, c) __builtin_amdgcn_mfma_f32_16x16x32_bf16((a), (b), (c), 0, 0, 0)

__device__ inline ushort f2bf(float f){           // round-to-nearest-even fp32->bf16
  uint32_t u = __float_as_uint(f);
  uint32_t r = (u + 0x7FFFu + ((u >> 16) & 1u)) >> 16;
  return (ushort)r;
}

// ---------------- graph preprocessing ----------------

__global__ void k_outdeg(const int* __restrict__ row, int* __restrict__ outdeg){
  int e = blockIdx.x * blockDim.x + threadIdx.x;
  if (e < EE) atomicAdd(&outdeg[row[e]], 1);
}

__global__ void k_fill(const int* __restrict__ row, const int* __restrict__ col,
                       const int* __restrict__ outdeg,
                       int* __restrict__ incnt, int* __restrict__ bsrc,
                       float* __restrict__ bnorm){
  int e = blockIdx.x * blockDim.x + threadIdx.x;
  if (e >= EE) return;
  int r = row[e], c = col[e];
  int j = atomicAdd(&incnt[c], 1);
  if (j < CAP){
    bsrc[(size_t)c * CAP + j]  = r;
    bnorm[(size_t)c * CAP + j] = 1.0f / fmaxf((float)outdeg[r], 1.0f);
  }
}

// ---------------- weight conversion: fp32 [K x NF] -> bf16 [NF x dstK] (transposed) ----

struct ConvJob { const float* src; ushort* dst; int K; int shift; int mask; int koff; int dstK; };
struct ConvJobs { ConvJob j[16]; };

__global__ void k_conv(ConvJobs J){
  ConvJob jb = J.j[blockIdx.x];
  int total = jb.K << jb.shift;
  for (int idx = threadIdx.x; idx < total; idx += 256){
    int f = idx & jb.mask, k = idx >> jb.shift;
    jb.dst[(size_t)f * jb.dstK + jb.koff + k] = f2bf(jb.src[idx]);
  }
}

// ---------------- aggregation: out[c] = sum_e w_e * hin[src_e] ----------------
// wave per node; 16 lanes x float4 per source row; 8 edges in flight per iter.

__global__ void __launch_bounds__(256) k_agg(const float* __restrict__ hin,
                                             float* __restrict__ out,
                                             const int* __restrict__ bsrc,
                                             const float* __restrict__ bnorm,
                                             const int* __restrict__ incnt,
                                             int use_norm){
  __shared__ int   sidx[4][CAP + 8];
  __shared__ float swgt[4][CAP + 8];
  int wib  = threadIdx.x >> 6;
  int lane = threadIdx.x & 63;
  int wid  = blockIdx.x * 4 + wib;
  bool valid = wid < NN;
  int cnt  = valid ? incnt[wid] : 0;
  int cntb = min(cnt, CAP);
  if (valid){
    int   si = (lane < cntb) ? bsrc[(size_t)wid * CAP + lane] : 0;
    float wv;
    if (use_norm) wv = (lane < cntb) ? bnorm[(size_t)wid * CAP + lane] : 0.f;
    else          wv = (lane < cntb) ? 1.0f / fmaxf((float)cnt, 1.f) : 0.f;
    sidx[wib][lane] = si;
    swgt[wib][lane] = wv;
    if (lane < 8){ sidx[wib][CAP + lane] = 0; swgt[wib][CAP + lane] = 0.f; }
  }
  __syncthreads();
  if (!valid) return;

  const float4* __restrict__ hin4 = (const float4*)hin;
  int g  = lane >> 4;
  int fl = lane & 15;
  float4 acc = {0.f, 0.f, 0.f, 0.f};
  for (int e0 = 0; e0 < cntb; e0 += 8){
    int ea = e0 + g, eb = e0 + g + 4;
    int   sa = sidx[wib][ea], sb = sidx[wib][eb];
    float wa = swgt[wib][ea], wb = swgt[wib][eb];
    float4 va = hin4[(size_t)sa * 16 + fl];
    float4 vb = hin4[(size_t)sb * 16 + fl];
    acc.x = fmaf(wa, va.x, acc.x); acc.y = fmaf(wa, va.y, acc.y);
    acc.z = fmaf(wa, va.z, acc.z); acc.w = fmaf(wa, va.w, acc.w);
    acc.x = fmaf(wb, vb.x, acc.x); acc.y = fmaf(wb, vb.y, acc.y);
    acc.z = fmaf(wb, vb.z, acc.z); acc.w = fmaf(wb, vb.w, acc.w);
  }
  #pragma unroll
  for (int m = 16; m < 64; m <<= 1){
    acc.x += __shfl_xor(acc.x, m);
    acc.y += __shfl_xor(acc.y, m);
    acc.z += __shfl_xor(acc.z, m);
    acc.w += __shfl_xor(acc.w, m);
  }
  if (lane < 16) ((float4*)out)[(size_t)wid * 16 + fl] = acc;
}

// ---------------- MFMA GEMM machinery ----------------
// Block: 256 threads = 4 waves, 64 rows. LDS tile: 64 rows x 64 bf16, stride 72 hw
// (144 B pad -> 2-way bank alias = free). All P piece-loads are issued up-front
// into registers (24 float4 in flight for P=6) so HBM latency is paid once, then
// each phase is {barrier, cvt+ds_write (vmcnt-gated), barrier, 2*NCT MFMA}.
// A-frag: row=lane&15, k=(lane>>4)*8+j. B-frag: col=lane&15 from WT[NF][K].
// C/D: col=lane&15, row=(lane>>4)*4+reg   [m89-verified]

__device__ inline s16x8 loadA(const ushort* sX, int wrow, int ks, int q){
  return *(const s16x8*)(sX + wrow * 72 + ks * 32 + q * 8);
}

__device__ inline s16x8 loadB(const ushort* __restrict__ WT, int dstK, int col, int kidx){
  return *(const s16x8*)(WT + (size_t)col * dstK + kidx);
}

template<int P, int NCT>
__device__ inline void gemm_core(const float* const* pieces, const ushort* __restrict__ WT,
                                 int dstK, int base, ushort* sX, f32x4* acc){
  int t = threadIdx.x;
  int lane = t & 63, wv = t >> 6;
  int q = lane >> 4, r16 = lane & 15;
  int wrow = wv * 16 + r16;
  int rr = t >> 4, c4 = (t & 15) << 2;

  float4 pref[P][4];
  #pragma unroll
  for (int p = 0; p < P; ++p){
    #pragma unroll
    for (int i = 0; i < 4; ++i){
      int n = base + rr + (i << 4);
      float4 z = {0.f, 0.f, 0.f, 0.f};
      pref[p][i] = (n < NN) ? *(const float4*)(pieces[p] + (size_t)n * 64 + c4) : z;
    }
  }

  #pragma unroll
  for (int p = 0; p < P; ++p){
    __syncthreads();
    #pragma unroll
    for (int i = 0; i < 4; ++i){
      int r = rr + (i << 4);
      ushort4 u;
      u.x = f2bf(pref[p][i].x); u.y = f2bf(pref[p][i].y);
      u.z = f2bf(pref[p][i].z); u.w = f2bf(pref[p][i].w);
      *(ushort4*)(sX + r * 72 + c4) = u;
    }
    __syncthreads();
    #pragma unroll
    for (int ks = 0; ks < 2; ++ks){
      s16x8 a = loadA(sX, wrow, ks, q);
      #pragma unroll
      for (int ct = 0; ct < NCT; ++ct){
        s16x8 b = loadB(WT, dstK, ct * 16 + r16, p * 64 + ks * 32 + q * 8);
        acc[ct] = MFMA16(a, b, acc[ct]);
      }
    }
  }
}

// ---- skip = x @ W_in + b_in ----
__global__ void __launch_bounds__(256) k_skip(const float* __restrict__ x,
                                              const ushort* __restrict__ WT,
                                              const float* __restrict__ bias,
                                              float* __restrict__ out){
  __shared__ __align__(16) ushort sX[4608];
  const float* pieces[1] = {x};
  f32x4 acc[4] = {};
  int base = blockIdx.x * 64;
  gemm_core<1, 4>(pieces, WT, 64, base, sX, acc);
  int lane = threadIdx.x & 63, wv = threadIdx.x >> 6, q = lane >> 4, r16 = lane & 15;
  #pragma unroll
  for (int ct = 0; ct < 4; ++ct){
    int col = ct * 16 + r16;
    float b = bias[col];
    #pragma unroll
    for (int r = 0; r < 4; ++r){
      int row = base + wv * 16 + q * 4 + r;
      if (row < NN) out[(size_t)row * 64 + col] = acc[ct][r] + b;
    }
  }
}

// ---- sage layer: out = relu(bn([mean|h]@[Wl;Wr] + bl)) + h ----
__global__ void __launch_bounds__(256) k_sage_m(const float* __restrict__ meanb,
                                                const float* __restrict__ h,
                                                const ushort* __restrict__ WT,
                                                const float* __restrict__ bl,
                                                const float* __restrict__ g,
                                                const float* __restrict__ be,
                                                const float* __restrict__ m_,
                                                const float* __restrict__ var_,
                                                float* __restrict__ hout){
  __shared__ __align__(16) ushort sX[4608];
  const float* pieces[2] = {meanb, h};
  f32x4 acc[4] = {};
  int base = blockIdx.x * 64;
  gemm_core<2, 4>(pieces, WT, 128, base, sX, acc);
  int lane = threadIdx.x & 63, wv = threadIdx.x >> 6, q = lane >> 4, r16 = lane & 15;
  #pragma unroll
  for (int ct = 0; ct < 4; ++ct){
    int col = ct * 16 + r16;
    float sc = g[col] * rsqrtf(var_[col] + EPS_BN);
    float sh = be[col] - m_[col] * sc;
    float bb = bl[col];
    #pragma unroll
    for (int r = 0; r < 4; ++r){
      int row = base + wv * 16 + q * 4 + r;
      if (row < NN){
        float t = (acc[ct][r] + bb) * sc + sh;
        hout[(size_t)row * 64 + col] = fmaxf(t, 0.f) + h[(size_t)row * 64 + col];
      }
    }
  }
}

// ---- YR: [h1..h4|skip|path](384) @ [vWl|vWr] -> Y (no bias), R (+vbl) ----
__global__ void __launch_bounds__(256) k_yr(const float* __restrict__ x0, const float* __restrict__ x1,
                                            const float* __restrict__ x2, const float* __restrict__ x3,
                                            const float* __restrict__ x4, const float* __restrict__ x5,
                                            const ushort* __restrict__ WT, const float* __restrict__ vbl,
                                            float* __restrict__ Y, float* __restrict__ R){
  __shared__ __align__(16) ushort sX[4608];
  const float* pieces[6] = {x0, x1, x2, x3, x4, x5};
  f32x4 acc[8] = {};
  int base = blockIdx.x * 64;
  gemm_core<6, 8>(pieces, WT, 384, base, sX, acc);
  int lane = threadIdx.x & 63, wv = threadIdx.x >> 6, q = lane >> 4, r16 = lane & 15;
  #pragma unroll
  for (int ct = 0; ct < 8; ++ct){
    int col = ct * 16 + r16;
    bool isR = col >= 64;
    int c2 = isR ? (col - 64) : col;
    float b = isR ? vbl[c2] : 0.f;
    float* dst = isR ? R : Y;
    #pragma unroll
    for (int r = 0; r < 4; ++r){
      int row = base + wv * 16 + q * 4 + r;
      if (row < NN) dst[(size_t)row * 64 + c2] = acc[ct][r] + b;
    }
  }
}

// ---- mulv: v = relu(bn(Yagg+R)); [mu|lv] = v @ [Wmu|Wlv] + [bmu|blv] ----
__global__ void __launch_bounds__(256) k_mulv_m(const float* __restrict__ Yagg,
                                                const float* __restrict__ R,
                                                const float* __restrict__ vg,
                                                const float* __restrict__ vbe,
                                                const float* __restrict__ vm,
                                                const float* __restrict__ vvar,
                                                const ushort* __restrict__ WT,
                                                const float* __restrict__ bmu,
                                                const float* __restrict__ blv,
                                                float* __restrict__ mu, float* __restrict__ lv){
  __shared__ __align__(16) ushort sX[4608];
  __shared__ float ssc[64], ssh[64];
  int t = threadIdx.x;
  if (t < 64){
    float sc = vg[t] * rsqrtf(vvar[t] + EPS_BN);
    ssc[t] = sc; ssh[t] = vbe[t] - vm[t] * sc;
  }
  __syncthreads();
  int base = blockIdx.x * 64;
  int rr = t >> 4, c4 = (t & 15) << 2;
  #pragma unroll
  for (int i = 0; i < 4; ++i){
    int r = rr + (i << 4);
    int n = base + r;
    float4 a = {0,0,0,0}, b = {0,0,0,0};
    if (n < NN){
      a = *(const float4*)(Yagg + (size_t)n * 64 + c4);
      b = *(const float4*)(R    + (size_t)n * 64 + c4);
    }
    ushort4 u;
    u.x = f2bf(fmaxf((a.x + b.x) * ssc[c4+0] + ssh[c4+0], 0.f));
    u.y = f2bf(fmaxf((a.y + b.y) * ssc[c4+1] + ssh[c4+1], 0.f));
    u.z = f2bf(fmaxf((a.z + b.z) * ssc[c4+2] + ssh[c4+2], 0.f));
    u.w = f2bf(fmaxf((a.w + b.w) * ssc[c4+3] + ssh[c4+3], 0.f));
    *(ushort4*)(sX + r * 72 + c4) = u;
  }
  __syncthreads();
  int lane = t & 63, wv = t >> 6, q = lane >> 4, r16 = lane & 15;
  int wrow = wv * 16 + r16;
  f32x4 acc[8] = {};
  #pragma unroll
  for (int ks = 0; ks < 2; ++ks){
    s16x8 a = loadA(sX, wrow, ks, q);
    #pragma unroll
    for (int ct = 0; ct < 8; ++ct){
      s16x8 b = loadB(WT, 64, ct * 16 + r16, ks * 32 + q * 8);
      acc[ct] = MFMA16(a, b, acc[ct]);
    }
  }
  #pragma unroll
  for (int ct = 0; ct < 8; ++ct){
    int col = ct * 16 + r16;
    bool isL = col >= 64;
    int c2 = isL ? (col - 64) : col;
    float b = isL ? blv[c2] : bmu[c2];
    float* dst = isL ? lv : mu;
    #pragma unroll
    for (int r = 0; r < 4; ++r){
      int row = base + wv * 16 + q * 4 + r;
      if (row < NN) dst[(size_t)row * 64 + c2] = acc[ct][r] + b;
    }
  }
}

// ---- rank = relu(mu@rW1+rb1) @ rW2 + rb2 ----
__global__ void __launch_bounds__(256) k_rank_m(const float* __restrict__ muv,
                                                const ushort* __restrict__ WT,
                                                const float* __restrict__ rb1,
                                                const float* __restrict__ rW2,
                                                const float* __restrict__ rb2,
                                                float* __restrict__ rout){
  __shared__ __align__(16) ushort sX[4608];
  const float* pieces[1] = {muv};
  f32x4 acc[4] = {};
  int base = blockIdx.x * 64;
  gemm_core<1, 4>(pieces, WT, 64, base, sX, acc);
  int lane = threadIdx.x & 63, wv = threadIdx.x >> 6, q = lane >> 4, r16 = lane & 15;
  float val[4] = {0.f, 0.f, 0.f, 0.f};
  #pragma unroll
  for (int ct = 0; ct < 4; ++ct){
    int col = ct * 16 + r16;
    float b1 = rb1[col], w2 = rW2[col];
    #pragma unroll
    for (int r = 0; r < 4; ++r)
      val[r] += fmaxf(acc[ct][r] + b1, 0.f) * w2;
  }
  #pragma unroll
  for (int r = 0; r < 4; ++r){
    #pragma unroll
    for (int m = 1; m < 16; m <<= 1) val[r] += __shfl_xor(val[r], m);
  }
  if (r16 == 0){
    float b2 = rb2[0];
    #pragma unroll
    for (int r = 0; r < 4; ++r){
      int row = base + wv * 16 + q * 4 + r;
      if (row < NN) rout[row] = val[r] + b2;
    }
  }
}

// ---- reg stage 1: h1 = relu([stage1|z](384)@gW1[0:384] + gb1 + rank*gW1[384]) ----
__global__ void __launch_bounds__(256) k_reg1(const float* __restrict__ x0, const float* __restrict__ x1,
                                              const float* __restrict__ x2, const float* __restrict__ x3,
                                              const float* __restrict__ x4, const float* __restrict__ x5,
                                              const float* __restrict__ rank,
                                              const ushort* __restrict__ WT,
                                              const float* __restrict__ gW1,   // fp32, for row 384
                                              const float* __restrict__ gb1,
                                              float* __restrict__ h1buf){
  __shared__ __align__(16) ushort sX[4608];
  const float* pieces[6] = {x0, x1, x2, x3, x4, x5};
  f32x4 acc[4] = {};
  int base = blockIdx.x * 64;
  gemm_core<6, 4>(pieces, WT, 384, base, sX, acc);
  int lane = threadIdx.x & 63, wv = threadIdx.x >> 6, q = lane >> 4, r16 = lane & 15;
  float rk[4];
  #pragma unroll
  for (int r = 0; r < 4; ++r){
    int row = base + wv * 16 + q * 4 + r;
    rk[r] = (row < NN) ? rank[row] : 0.f;
  }
  #pragma unroll
  for (int ct = 0; ct < 4; ++ct){
    int col = ct * 16 + r16;
    float b1 = gb1[col];
    float w384 = gW1[384 * 64 + col];
    #pragma unroll
    for (int r = 0; r < 4; ++r){
      int row = base + wv * 16 + q * 4 + r;
      if (row < NN)
        h1buf[(size_t)row * 64 + col] = fmaxf(acc[ct][r] + b1 + rk[r] * w384, 0.f);
    }
  }
}

// ---- reg tail: h2 = relu(h1@gW2+gb2); preds = h2@gW3 + gb3 ----
__global__ void __launch_bounds__(256) k_reg2(const float* __restrict__ h1buf,
                                              const ushort* __restrict__ WT,
                                              const float* __restrict__ gb2,
                                              const float* __restrict__ gW3,
                                              const float* __restrict__ gb3,
                                              float* __restrict__ preds){
  __shared__ __align__(16) ushort sX[4608];
  const float* pieces[1] = {h1buf};
  f32x4 acc[2] = {};
  int base = blockIdx.x * 64;
  gemm_core<1, 2>(pieces, WT, 64, base, sX, acc);
  int lane = threadIdx.x & 63, wv = threadIdx.x >> 6, q = lane >> 4, r16 = lane & 15;
  float val[4] = {0.f, 0.f, 0.f, 0.f};
  #pragma unroll
  for (int ct = 0; ct < 2; ++ct){
    int col = ct * 16 + r16;       // 0..31
    float b2 = gb2[col], w3 = gW3[col];
    #pragma unroll
    for (int r = 0; r < 4; ++r)
      val[r] += fmaxf(acc[ct][r] + b2, 0.f) * w3;
  }
  #pragma unroll
  for (int r = 0; r < 4; ++r){
    #pragma unroll
    for (int m = 1; m < 16; m <<= 1) val[r] += __shfl_xor(val[r], m);
  }
  if (r16 == 0){
    float b3 = gb3[0];
    #pragma unroll
    for (int r = 0; r < 4; ++r){
      int row = base + wv * 16 + q * 4 + r;
      if (row < NN) preds[row] = val[r] + b3;
    }
  }
}

// ---------------- launch ----------------

extern "C" void kernel_launch(void* const* d_in, const int* in_sizes, int n_in,
                              void* d_out, int out_size, void* d_ws, size_t ws_size,
                              hipStream_t stream){
  const float* x    = (const float*)d_in[0];
  const int*   eidx = (const int*)d_in[1];
  const int* row = eidx;
  const int* col = eidx + EE;
  const float* W_in = (const float*)d_in[2];
  const float* b_in = (const float*)d_in[3];
  const float* sWl  = (const float*)d_in[4];
  const float* sbl  = (const float*)d_in[5];
  const float* sWr  = (const float*)d_in[6];
  const float* bng  = (const float*)d_in[7];
  const float* bnb  = (const float*)d_in[8];
  const float* bnm  = (const float*)d_in[9];
  const float* bnv  = (const float*)d_in[10];
  const float* vWl  = (const float*)d_in[11];
  const float* vbl  = (const float*)d_in[12];
  const float* vWr  = (const float*)d_in[13];
  const float* vg   = (const float*)d_in[14];
  const float* vbe  = (const float*)d_in[15];
  const float* vm   = (const float*)d_in[16];
  const float* vvar = (const float*)d_in[17];
  const float* Wmu  = (const float*)d_in[18];
  const float* bmu  = (const float*)d_in[19];
  const float* Wlv  = (const float*)d_in[20];
  const float* blv  = (const float*)d_in[21];
  const float* rW1  = (const float*)d_in[22];
  const float* rb1  = (const float*)d_in[23];
  const float* rW2  = (const float*)d_in[24];
  const float* rb2  = (const float*)d_in[25];
  const float* gW1  = (const float*)d_in[26];
  const float* gb1  = (const float*)d_in[27];
  const float* gW2  = (const float*)d_in[28];
  const float* gb2  = (const float*)d_in[29];
  const float* gW3  = (const float*)d_in[30];
  const float* gb3  = (const float*)d_in[31];

  float* preds = (float*)d_out;
  float* rank  = preds + NN;
  float* mu    = rank + NN;
  float* lv    = mu + (size_t)NN * 64;

  char* w = (char*)d_ws;
  auto alloc = [&](size_t bytes) -> char* {
    char* p = w; w += (bytes + 255) & ~(size_t)255; return p;
  };
  int*   outdeg = (int*)alloc((size_t)NN * 4);
  int*   incnt  = (int*)alloc((size_t)NN * 4);
  int*   bsrc   = (int*)alloc((size_t)NN * CAP * 4);
  float* bnorm  = (float*)alloc((size_t)NN * CAP * 4);
  float* skip   = (float*)alloc((size_t)NN * 64 * 4);
  float* hl[4];
  for (int i = 0; i < 4; ++i) hl[i] = (float*)alloc((size_t)NN * 64 * 4);
  float* meanb  = (float*)alloc((size_t)NN * 64 * 4);
  float* pa     = (float*)alloc((size_t)NN * 64 * 4);   // also reused as h1buf
  float* pb     = (float*)alloc((size_t)NN * 64 * 4);
  float* Yb     = (float*)alloc((size_t)NN * 64 * 4);
  float* Rb     = (float*)alloc((size_t)NN * 64 * 4);
  ushort* skipW = (ushort*)alloc(64 * 64 * 2);
  ushort* sageW = (ushort*)alloc(4 * 64 * 128 * 2);
  ushort* yrW   = (ushort*)alloc(128 * 384 * 2);
  ushort* mulvW = (ushort*)alloc(128 * 64 * 2);
  ushort* rankW = (ushort*)alloc(64 * 64 * 2);
  ushort* regW1 = (ushort*)alloc(64 * 384 * 2);
  ushort* regW2 = (ushort*)alloc(32 * 64 * 2);

  hipMemsetAsync(outdeg, 0, (size_t)NN * 4, stream);
  hipMemsetAsync(incnt,  0, (size_t)NN * 4, stream);

  const int EB = (EE + 255) / 256;
  k_outdeg<<<EB, 256, 0, stream>>>(row, outdeg);
  k_fill  <<<EB, 256, 0, stream>>>(row, col, outdeg, incnt, bsrc, bnorm);

  // weight conversions (16 jobs, 1 block each)
  ConvJobs J;
  auto job = [&](int i, const float* s, ushort* d, int K, int shift, int koff, int dstK){
    J.j[i] = {s, d, K, shift, (1 << shift) - 1, koff, dstK};
  };
  job(0,  W_in, skipW, 64, 6, 0, 64);
  for (int i = 0; i < 4; ++i){
    job(1 + i, sWl + i * 4096, sageW + i * 8192, 64, 6, 0,  128);
    job(5 + i, sWr + i * 4096, sageW + i * 8192, 64, 6, 64, 128);
  }
  job(9,  vWl, yrW,            384, 6, 0, 384);
  job(10, vWr, yrW + 64 * 384, 384, 6, 0, 384);
  job(11, Wmu, mulvW,           64, 6, 0, 64);
  job(12, Wlv, mulvW + 64 * 64, 64, 6, 0, 64);
  job(13, rW1, rankW,           64, 6, 0, 64);
  job(14, gW1, regW1,          384, 6, 0, 384);
  job(15, gW2, regW2,           64, 5, 0, 64);
  k_conv<<<16, 256, 0, stream>>>(J);

  const int GB = (NN + 63) / 64;   // 782 row-tile blocks
  k_skip<<<GB, 256, 0, stream>>>(x, skipW, b_in, skip);

  const int AGG_B = (NN + 3) / 4;
  const float* hprev = x;
  for (int i = 0; i < 4; ++i){
    k_agg<<<AGG_B, 256, 0, stream>>>(hprev, meanb, bsrc, bnorm, incnt, 0);
    k_sage_m<<<GB, 256, 0, stream>>>(meanb, hprev, sageW + i * 8192, sbl + i * 64,
                                     bng + i * 64, bnb + i * 64, bnm + i * 64, bnv + i * 64, hl[i]);
    hprev = hl[i];
  }

  k_agg<<<AGG_B, 256, 0, stream>>>(hl[3], pa, bsrc, bnorm, incnt, 1);
  k_agg<<<AGG_B, 256, 0, stream>>>(pa, pb, bsrc, bnorm, incnt, 1);
  k_agg<<<AGG_B, 256, 0, stream>>>(pb, pa, bsrc, bnorm, incnt, 1);
  k_agg<<<AGG_B, 256, 0, stream>>>(pa, pb, bsrc, bnorm, incnt, 1);
  // path_out = pb

  k_yr<<<GB, 256, 0, stream>>>(hl[0], hl[1], hl[2], hl[3], skip, pb, yrW, vbl, Yb, Rb);
  k_agg<<<AGG_B, 256, 0, stream>>>(Yb, meanb, bsrc, bnorm, incnt, 0);
  k_mulv_m<<<GB, 256, 0, stream>>>(meanb, Rb, vg, vbe, vm, vvar, mulvW, bmu, blv, mu, lv);
  k_rank_m<<<GB, 256, 0, stream>>>(mu, rankW, rb1, rW2, rb2, rank);
  k_reg1<<<GB, 256, 0, stream>>>(hl[0], hl[1], hl[2], hl[3], skip, mu, rank,
                                 regW1, gW1, gb1, pa);
  k_reg2<<<GB, 256, 0, stream>>>(pa, regW2, gb2, gW3, gb3, preds);
}

// Round 6
// 623.436 us; speedup vs baseline: 1.1461x; 1.1461x over previous
//
#include <hip/hip_runtime.h>
#include <cstdint>
#include <cstddef>

#define NN 50000
#define EE 800000
#define CAP 64
#define EPS_BN 1e-5f

typedef short  s16x8 __attribute__((ext_vector_type(8)));
typedef ushort u16x8 __attribute__((ext_vector_type(8)));
typedef float  f32x4 __attribute__((ext_vector_type(4)));

#define MFMA16(a, b, c) __builtin_amdgcn_mfma_f32_16x16x32_bf16((a), (b), (c), 0, 0, 0)

__device__ inline ushort f2bf(float f){           // round-to-nearest-even fp32->bf16
  uint32_t u = __float_as_uint(f);
  uint32_t r = (u + 0x7FFFu + ((u >> 16) & 1u)) >> 16;
  return (ushort)r;
}
__device__ inline float bf2f(ushort u){ return __uint_as_float((uint32_t)u << 16); }

// ---------------- graph preprocessing ----------------

__global__ void k_outdeg(const int* __restrict__ row, int* __restrict__ outdeg){
  int e = blockIdx.x * blockDim.x + threadIdx.x;
  if (e < EE) atomicAdd(&outdeg[row[e]], 1);
}

__global__ void k_fill(const int* __restrict__ row, const int* __restrict__ col,
                       const int* __restrict__ outdeg,
                       int* __restrict__ incnt, int* __restrict__ bsrc,
                       float* __restrict__ bnorm){
  int e = blockIdx.x * blockDim.x + threadIdx.x;
  if (e >= EE) return;
  int r = row[e], c = col[e];
  int j = atomicAdd(&incnt[c], 1);
  if (j < CAP){
    bsrc[(size_t)c * CAP + j]  = r;
    bnorm[(size_t)c * CAP + j] = 1.0f / fmaxf((float)outdeg[r], 1.0f);
  }
}

// ---------------- fp32 -> bf16 bulk convert ----------------

__global__ void k_cvt(const float* __restrict__ src, ushort* __restrict__ dst, int n4){
  int i = blockIdx.x * blockDim.x + threadIdx.x;
  int stride = gridDim.x * blockDim.x;
  for (; i < n4; i += stride){
    float4 v = ((const float4*)src)[i];
    ushort4 u = {f2bf(v.x), f2bf(v.y), f2bf(v.z), f2bf(v.w)};
    ((ushort4*)dst)[i] = u;
  }
}

// ---------------- weight conversion: fp32 [K x NF] -> bf16 [NF x dstK] (transposed) ----

struct ConvJob { const float* src; ushort* dst; int K; int shift; int mask; int koff; int dstK; };
struct ConvJobs { ConvJob j[16]; };

__global__ void k_conv(ConvJobs J){
  ConvJob jb = J.j[blockIdx.x];
  int total = jb.K << jb.shift;
  for (int idx = threadIdx.x; idx < total; idx += 256){
    int f = idx & jb.mask, k = idx >> jb.shift;
    jb.dst[(size_t)f * jb.dstK + jb.koff + k] = f2bf(jb.src[idx]);
  }
}

// ---------------- aggregation (bf16 in/out): out[c] = sum_e w_e * hin[src_e] --------
// wave per node; 8 lanes x 16B per source row; 8 edges in flight per iter.

__global__ void __launch_bounds__(256) k_agg(const ushort* __restrict__ hin,
                                             ushort* __restrict__ out,
                                             const int* __restrict__ bsrc,
                                             const float* __restrict__ bnorm,
                                             const int* __restrict__ incnt,
                                             int use_norm){
  __shared__ int   sidx[4][CAP];
  __shared__ float swgt[4][CAP];
  int wib  = threadIdx.x >> 6;
  int lane = threadIdx.x & 63;
  int wid  = blockIdx.x * 4 + wib;
  bool valid = wid < NN;
  int cnt  = valid ? incnt[wid] : 0;
  int cntb = min(cnt, CAP);
  if (valid){
    int   si = (lane < cntb) ? bsrc[(size_t)wid * CAP + lane] : 0;
    float wv;
    if (use_norm) wv = (lane < cntb) ? bnorm[(size_t)wid * CAP + lane] : 0.f;
    else          wv = (lane < cntb) ? 1.0f / fmaxf((float)cnt, 1.f) : 0.f;
    sidx[wib][lane] = si;
    swgt[wib][lane] = wv;
  }
  __syncthreads();
  if (!valid) return;

  int g  = lane >> 3;     // edge slot within oct (0..7)
  int fl = lane & 7;      // 16B feature chunk (8 bf16)
  float accf[8] = {0,0,0,0,0,0,0,0};
  for (int e0 = 0; e0 < cntb; e0 += 8){
    int e = e0 + g;                       // <= 63 always
    int   s = sidx[wib][e];
    float w = swgt[wib][e];
    u16x8 v = *(const u16x8*)(hin + (size_t)s * 64 + fl * 8);
    #pragma unroll
    for (int j = 0; j < 8; ++j) accf[j] = fmaf(w, bf2f(v[j]), accf[j]);
  }
  #pragma unroll
  for (int m = 8; m < 64; m <<= 1){
    #pragma unroll
    for (int j = 0; j < 8; ++j) accf[j] += __shfl_xor(accf[j], m);
  }
  if (lane < 8){
    u16x8 o;
    #pragma unroll
    for (int j = 0; j < 8; ++j) o[j] = f2bf(accf[j]);
    *(u16x8*)(out + (size_t)wid * 64 + lane * 8) = o;
  }
}

// ---------------- direct-load MFMA GEMM (no LDS, no barriers) ----------------
// Wave handles 16 rows. A-frag: 16B global load from bf16 [N][64] row-major at
// row=rowbase+(lane&15), k=(lane>>4)*8. B-frag from WT[NF][dstK] bf16.
// C/D: col=lane&15 (within 16-tile), row=(lane>>4)*4+reg  [m89-verified]

template<int P, int NCT>
__device__ inline void gemm_direct(const ushort* const* pieces,
                                   const ushort* __restrict__ WT,
                                   int dstK, int rowbase, f32x4* acc){
  int lane = threadIdx.x & 63;
  int q = lane >> 4, r16 = lane & 15;
  int ar = rowbase + r16; ar = (ar < NN) ? ar : (NN - 1);
  #pragma unroll
  for (int p = 0; p < P; ++p){
    const ushort* src = pieces[p] + (size_t)ar * 64 + q * 8;
    #pragma unroll
    for (int ks = 0; ks < 2; ++ks){
      s16x8 a = *(const s16x8*)(src + ks * 32);
      const ushort* wb = WT + (size_t)r16 * dstK + p * 64 + ks * 32 + q * 8;
      #pragma unroll
      for (int ct = 0; ct < NCT; ++ct){
        s16x8 b = *(const s16x8*)(wb + (size_t)ct * 16 * dstK);
        acc[ct] = MFMA16(a, b, acc[ct]);
      }
    }
  }
}

// ---- skip = x @ W_in + b_in  (bf16 out) ----
__global__ void __launch_bounds__(256) k_skip(const ushort* __restrict__ xb,
                                              const ushort* __restrict__ WT,
                                              const float* __restrict__ bias,
                                              ushort* __restrict__ outb){
  int lane = threadIdx.x & 63, wv = threadIdx.x >> 6, q = lane >> 4, r16 = lane & 15;
  int rowbase = blockIdx.x * 64 + wv * 16;
  const ushort* pieces[1] = {xb};
  f32x4 acc[4] = {};
  gemm_direct<1, 4>(pieces, WT, 64, rowbase, acc);
  #pragma unroll
  for (int ct = 0; ct < 4; ++ct){
    int col = ct * 16 + r16;
    float b = bias[col];
    #pragma unroll
    for (int r = 0; r < 4; ++r){
      int row = rowbase + q * 4 + r;
      if (row < NN) outb[(size_t)row * 64 + col] = f2bf(acc[ct][r] + b);
    }
  }
}

// ---- sage layer: out = relu(bn([mean|h]@[Wl;Wr] + bl)) + h   (bf16 in/out) ----
__global__ void __launch_bounds__(256) k_sage_m(const ushort* __restrict__ meanb,
                                                const ushort* __restrict__ hb,
                                                const ushort* __restrict__ WT,
                                                const float* __restrict__ bl,
                                                const float* __restrict__ g,
                                                const float* __restrict__ be,
                                                const float* __restrict__ m_,
                                                const float* __restrict__ var_,
                                                ushort* __restrict__ houtb){
  int lane = threadIdx.x & 63, wv = threadIdx.x >> 6, q = lane >> 4, r16 = lane & 15;
  int rowbase = blockIdx.x * 64 + wv * 16;
  const ushort* pieces[2] = {meanb, hb};
  f32x4 acc[4] = {};
  gemm_direct<2, 4>(pieces, WT, 128, rowbase, acc);
  #pragma unroll
  for (int ct = 0; ct < 4; ++ct){
    int col = ct * 16 + r16;
    float sc = g[col] * rsqrtf(var_[col] + EPS_BN);
    float sh = be[col] - m_[col] * sc;
    float bb = bl[col];
    #pragma unroll
    for (int r = 0; r < 4; ++r){
      int row = rowbase + q * 4 + r;
      if (row < NN){
        float t = (acc[ct][r] + bb) * sc + sh;
        float hv = bf2f(hb[(size_t)row * 64 + col]);
        houtb[(size_t)row * 64 + col] = f2bf(fmaxf(t, 0.f) + hv);
      }
    }
  }
}

// ---- YR: [h1..h4|skip|path](384) @ [vWl|vWr] -> Y, R(+vbl)   (bf16 out) ----
__global__ void __launch_bounds__(256) k_yr(const ushort* __restrict__ x0, const ushort* __restrict__ x1,
                                            const ushort* __restrict__ x2, const ushort* __restrict__ x3,
                                            const ushort* __restrict__ x4, const ushort* __restrict__ x5,
                                            const ushort* __restrict__ WT, const float* __restrict__ vbl,
                                            ushort* __restrict__ Y, ushort* __restrict__ R){
  int lane = threadIdx.x & 63, wv = threadIdx.x >> 6, q = lane >> 4, r16 = lane & 15;
  int rowbase = blockIdx.x * 64 + wv * 16;
  const ushort* pieces[6] = {x0, x1, x2, x3, x4, x5};
  f32x4 acc[8] = {};
  gemm_direct<6, 8>(pieces, WT, 384, rowbase, acc);
  #pragma unroll
  for (int ct = 0; ct < 8; ++ct){
    int col = ct * 16 + r16;
    bool isR = col >= 64;
    int c2 = isR ? (col - 64) : col;
    float b = isR ? vbl[c2] : 0.f;
    ushort* dst = isR ? R : Y;
    #pragma unroll
    for (int r = 0; r < 4; ++r){
      int row = rowbase + q * 4 + r;
      if (row < NN) dst[(size_t)row * 64 + c2] = f2bf(acc[ct][r] + b);
    }
  }
}

// ---- mulv: v = relu(bn(Yagg+R)); [mu|lv] = v @ [Wmu|Wlv] + [bmu|blv] ----
__global__ void __launch_bounds__(256) k_mulv_m(const ushort* __restrict__ Yagg,
                                                const ushort* __restrict__ Rb,
                                                const float* __restrict__ vg,
                                                const float* __restrict__ vbe,
                                                const float* __restrict__ vm,
                                                const float* __restrict__ vvar,
                                                const ushort* __restrict__ WT,
                                                const float* __restrict__ bmu,
                                                const float* __restrict__ blv,
                                                float* __restrict__ muf, float* __restrict__ lvf,
                                                ushort* __restrict__ mub){
  __shared__ float ssc[64], ssh[64];
  int t = threadIdx.x;
  if (t < 64){
    float sc = vg[t] * rsqrtf(vvar[t] + EPS_BN);
    ssc[t] = sc; ssh[t] = vbe[t] - vm[t] * sc;
  }
  __syncthreads();
  int lane = t & 63, wv = t >> 6, q = lane >> 4, r16 = lane & 15;
  int rowbase = blockIdx.x * 64 + wv * 16;
  int ar = rowbase + r16; ar = (ar < NN) ? ar : (NN - 1);
  f32x4 acc[8] = {};
  #pragma unroll
  for (int ks = 0; ks < 2; ++ks){
    int k0 = ks * 32 + q * 8;
    u16x8 y  = *(const u16x8*)(Yagg + (size_t)ar * 64 + k0);
    u16x8 rv = *(const u16x8*)(Rb   + (size_t)ar * 64 + k0);
    s16x8 a;
    #pragma unroll
    for (int j = 0; j < 8; ++j){
      float tv = (bf2f(y[j]) + bf2f(rv[j])) * ssc[k0 + j] + ssh[k0 + j];
      a[j] = (short)f2bf(fmaxf(tv, 0.f));
    }
    const ushort* wb = WT + (size_t)r16 * 64 + k0;
    #pragma unroll
    for (int ct = 0; ct < 8; ++ct){
      s16x8 b = *(const s16x8*)(wb + (size_t)ct * 16 * 64);
      acc[ct] = MFMA16(a, b, acc[ct]);
    }
  }
  #pragma unroll
  for (int ct = 0; ct < 8; ++ct){
    int col = ct * 16 + r16;
    bool isL = col >= 64;
    int c2 = isL ? (col - 64) : col;
    float bb = isL ? blv[c2] : bmu[c2];
    #pragma unroll
    for (int r = 0; r < 4; ++r){
      int row = rowbase + q * 4 + r;
      if (row < NN){
        float v = acc[ct][r] + bb;
        if (isL) lvf[(size_t)row * 64 + c2] = v;
        else { muf[(size_t)row * 64 + c2] = v; mub[(size_t)row * 64 + c2] = f2bf(v); }
      }
    }
  }
}

// ---- rank = relu(mu@rW1+rb1) @ rW2 + rb2 ----
__global__ void __launch_bounds__(256) k_rank_m(const ushort* __restrict__ mub,
                                                const ushort* __restrict__ WT,
                                                const float* __restrict__ rb1,
                                                const float* __restrict__ rW2,
                                                const float* __restrict__ rb2,
                                                float* __restrict__ rout){
  int lane = threadIdx.x & 63, wv = threadIdx.x >> 6, q = lane >> 4, r16 = lane & 15;
  int rowbase = blockIdx.x * 64 + wv * 16;
  const ushort* pieces[1] = {mub};
  f32x4 acc[4] = {};
  gemm_direct<1, 4>(pieces, WT, 64, rowbase, acc);
  float val[4] = {0.f, 0.f, 0.f, 0.f};
  #pragma unroll
  for (int ct = 0; ct < 4; ++ct){
    int col = ct * 16 + r16;
    float b1 = rb1[col], w2 = rW2[col];
    #pragma unroll
    for (int r = 0; r < 4; ++r)
      val[r] += fmaxf(acc[ct][r] + b1, 0.f) * w2;
  }
  #pragma unroll
  for (int r = 0; r < 4; ++r){
    #pragma unroll
    for (int m = 1; m < 16; m <<= 1) val[r] += __shfl_xor(val[r], m);
  }
  if (r16 == 0){
    float b2 = rb2[0];
    #pragma unroll
    for (int r = 0; r < 4; ++r){
      int row = rowbase + q * 4 + r;
      if (row < NN) rout[row] = val[r] + b2;
    }
  }
}

// ---- reg stage 1: h1 = relu([stage1|z](384)@gW1[0:384] + gb1 + rank*gW1[384]) ----
__global__ void __launch_bounds__(256) k_reg1(const ushort* __restrict__ x0, const ushort* __restrict__ x1,
                                              const ushort* __restrict__ x2, const ushort* __restrict__ x3,
                                              const ushort* __restrict__ x4, const ushort* __restrict__ x5,
                                              const float* __restrict__ rank,
                                              const ushort* __restrict__ WT,
                                              const float* __restrict__ gW1,   // fp32, for row 384
                                              const float* __restrict__ gb1,
                                              ushort* __restrict__ h1b){
  int lane = threadIdx.x & 63, wv = threadIdx.x >> 6, q = lane >> 4, r16 = lane & 15;
  int rowbase = blockIdx.x * 64 + wv * 16;
  const ushort* pieces[6] = {x0, x1, x2, x3, x4, x5};
  f32x4 acc[4] = {};
  gemm_direct<6, 4>(pieces, WT, 384, rowbase, acc);
  float rk[4];
  #pragma unroll
  for (int r = 0; r < 4; ++r){
    int row = rowbase + q * 4 + r;
    rk[r] = (row < NN) ? rank[row] : 0.f;
  }
  #pragma unroll
  for (int ct = 0; ct < 4; ++ct){
    int col = ct * 16 + r16;
    float b1 = gb1[col];
    float w384 = gW1[384 * 64 + col];
    #pragma unroll
    for (int r = 0; r < 4; ++r){
      int row = rowbase + q * 4 + r;
      if (row < NN)
        h1b[(size_t)row * 64 + col] = f2bf(fmaxf(acc[ct][r] + b1 + rk[r] * w384, 0.f));
    }
  }
}

// ---- reg tail: h2 = relu(h1@gW2+gb2); preds = h2@gW3 + gb3 ----
__global__ void __launch_bounds__(256) k_reg2(const ushort* __restrict__ h1b,
                                              const ushort* __restrict__ WT,
                                              const float* __restrict__ gb2,
                                              const float* __restrict__ gW3,
                                              const float* __restrict__ gb3,
                                              float* __restrict__ preds){
  int lane = threadIdx.x & 63, wv = threadIdx.x >> 6, q = lane >> 4, r16 = lane & 15;
  int rowbase = blockIdx.x * 64 + wv * 16;
  const ushort* pieces[1] = {h1b};
  f32x4 acc[2] = {};
  gemm_direct<1, 2>(pieces, WT, 64, rowbase, acc);
  float val[4] = {0.f, 0.f, 0.f, 0.f};
  #pragma unroll
  for (int ct = 0; ct < 2; ++ct){
    int col = ct * 16 + r16;       // 0..31
    float b2 = gb2[col], w3 = gW3[col];
    #pragma unroll
    for (int r = 0; r < 4; ++r)
      val[r] += fmaxf(acc[ct][r] + b2, 0.f) * w3;
  }
  #pragma unroll
  for (int r = 0; r < 4; ++r){
    #pragma unroll
    for (int m = 1; m < 16; m <<= 1) val[r] += __shfl_xor(val[r], m);
  }
  if (r16 == 0){
    float b3 = gb3[0];
    #pragma unroll
    for (int r = 0; r < 4; ++r){
      int row = rowbase + q * 4 + r;
      if (row < NN) preds[row] = val[r] + b3;
    }
  }
}

// ---------------- launch ----------------

extern "C" void kernel_launch(void* const* d_in, const int* in_sizes, int n_in,
                              void* d_out, int out_size, void* d_ws, size_t ws_size,
                              hipStream_t stream){
  const float* x    = (const float*)d_in[0];
  const int*   eidx = (const int*)d_in[1];
  const int* row = eidx;
  const int* col = eidx + EE;
  const float* W_in = (const float*)d_in[2];
  const float* b_in = (const float*)d_in[3];
  const float* sWl  = (const float*)d_in[4];
  const float* sbl  = (const float*)d_in[5];
  const float* sWr  = (const float*)d_in[6];
  const float* bng  = (const float*)d_in[7];
  const float* bnb  = (const float*)d_in[8];
  const float* bnm  = (const float*)d_in[9];
  const float* bnv  = (const float*)d_in[10];
  const float* vWl  = (const float*)d_in[11];
  const float* vbl  = (const float*)d_in[12];
  const float* vWr  = (const float*)d_in[13];
  const float* vg   = (const float*)d_in[14];
  const float* vbe  = (const float*)d_in[15];
  const float* vm   = (const float*)d_in[16];
  const float* vvar = (const float*)d_in[17];
  const float* Wmu  = (const float*)d_in[18];
  const float* bmu  = (const float*)d_in[19];
  const float* Wlv  = (const float*)d_in[20];
  const float* blv  = (const float*)d_in[21];
  const float* rW1  = (const float*)d_in[22];
  const float* rb1  = (const float*)d_in[23];
  const float* rW2  = (const float*)d_in[24];
  const float* rb2  = (const float*)d_in[25];
  const float* gW1  = (const float*)d_in[26];
  const float* gb1  = (const float*)d_in[27];
  const float* gW2  = (const float*)d_in[28];
  const float* gb2  = (const float*)d_in[29];
  const float* gW3  = (const float*)d_in[30];
  const float* gb3  = (const float*)d_in[31];

  float* preds = (float*)d_out;
  float* rank  = preds + NN;
  float* mu    = rank + NN;
  float* lv    = mu + (size_t)NN * 64;

  char* w = (char*)d_ws;
  auto alloc = [&](size_t bytes) -> char* {
    char* p = w; w += (bytes + 255) & ~(size_t)255; return p;
  };
  int*   outdeg = (int*)alloc((size_t)NN * 4);
  int*   incnt  = (int*)alloc((size_t)NN * 4);
  int*   bsrc   = (int*)alloc((size_t)NN * CAP * 4);
  float* bnorm  = (float*)alloc((size_t)NN * CAP * 4);
  const size_t FB = (size_t)NN * 64 * 2;           // bf16 feature buffer
  ushort* xb    = (ushort*)alloc(FB);
  ushort* skipb = (ushort*)alloc(FB);
  ushort* hb[4];
  for (int i = 0; i < 4; ++i) hb[i] = (ushort*)alloc(FB);
  ushort* meanb = (ushort*)alloc(FB);
  ushort* pa    = (ushort*)alloc(FB);              // path scratch; reused as h1buf
  ushort* pb    = (ushort*)alloc(FB);
  ushort* Yb    = (ushort*)alloc(FB);
  ushort* Rb    = (ushort*)alloc(FB);
  ushort* mub   = (ushort*)alloc(FB);
  ushort* skipW = (ushort*)alloc(64 * 64 * 2);
  ushort* sageW = (ushort*)alloc(4 * 64 * 128 * 2);
  ushort* yrW   = (ushort*)alloc(128 * 384 * 2);
  ushort* mulvW = (ushort*)alloc(128 * 64 * 2);
  ushort* rankW = (ushort*)alloc(64 * 64 * 2);
  ushort* regW1 = (ushort*)alloc(64 * 384 * 2);
  ushort* regW2 = (ushort*)alloc(32 * 64 * 2);

  hipMemsetAsync(outdeg, 0, (size_t)NN * 4, stream);
  hipMemsetAsync(incnt,  0, (size_t)NN * 4, stream);

  const int EB = (EE + 255) / 256;
  k_outdeg<<<EB, 256, 0, stream>>>(row, outdeg);
  k_fill  <<<EB, 256, 0, stream>>>(row, col, outdeg, incnt, bsrc, bnorm);

  // weight conversions (16 jobs, 1 block each)
  ConvJobs J;
  auto job = [&](int i, const float* s, ushort* d, int K, int shift, int koff, int dstK){
    J.j[i] = {s, d, K, shift, (1 << shift) - 1, koff, dstK};
  };
  job(0,  W_in, skipW, 64, 6, 0, 64);
  for (int i = 0; i < 4; ++i){
    job(1 + i, sWl + i * 4096, sageW + i * 8192, 64, 6, 0,  128);
    job(5 + i, sWr + i * 4096, sageW + i * 8192, 64, 6, 64, 128);
  }
  job(9,  vWl, yrW,            384, 6, 0, 384);
  job(10, vWr, yrW + 64 * 384, 384, 6, 0, 384);
  job(11, Wmu, mulvW,           64, 6, 0, 64);
  job(12, Wlv, mulvW + 64 * 64, 64, 6, 0, 64);
  job(13, rW1, rankW,           64, 6, 0, 64);
  job(14, gW1, regW1,          384, 6, 0, 384);
  job(15, gW2, regW2,           64, 5, 0, 64);
  k_conv<<<16, 256, 0, stream>>>(J);

  k_cvt<<<1024, 256, 0, stream>>>(x, xb, NN * 64 / 4);

  const int GB = (NN + 63) / 64;   // 782 row-tile blocks
  k_skip<<<GB, 256, 0, stream>>>(xb, skipW, b_in, skipb);

  const int AGG_B = (NN + 3) / 4;
  const ushort* hprev = xb;
  for (int i = 0; i < 4; ++i){
    k_agg<<<AGG_B, 256, 0, stream>>>(hprev, meanb, bsrc, bnorm, incnt, 0);
    k_sage_m<<<GB, 256, 0, stream>>>(meanb, hprev, sageW + i * 8192, sbl + i * 64,
                                     bng + i * 64, bnb + i * 64, bnm + i * 64, bnv + i * 64, hb[i]);
    hprev = hb[i];
  }

  k_agg<<<AGG_B, 256, 0, stream>>>(hb[3], pa, bsrc, bnorm, incnt, 1);
  k_agg<<<AGG_B, 256, 0, stream>>>(pa, pb, bsrc, bnorm, incnt, 1);
  k_agg<<<AGG_B, 256, 0, stream>>>(pb, pa, bsrc, bnorm, incnt, 1);
  k_agg<<<AGG_B, 256, 0, stream>>>(pa, pb, bsrc, bnorm, incnt, 1);
  // path_out = pb

  k_yr<<<GB, 256, 0, stream>>>(hb[0], hb[1], hb[2], hb[3], skipb, pb, yrW, vbl, Yb, Rb);
  k_agg<<<AGG_B, 256, 0, stream>>>(Yb, meanb, bsrc, bnorm, incnt, 0);
  k_mulv_m<<<GB, 256, 0, stream>>>(meanb, Rb, vg, vbe, vm, vvar, mulvW, bmu, blv, mu, lv, mub);
  k_rank_m<<<GB, 256, 0, stream>>>(mub, rankW, rb1, rW2, rb2, rank);
  k_reg1<<<GB, 256, 0, stream>>>(hb[0], hb[1], hb[2], hb[3], skipb, mub, rank,
                                 regW1, gW1, gb1, pa);
  k_reg2<<<GB, 256, 0, stream>>>(pa, regW2, gb2, gW3, gb3, preds);
}

// Round 8
// 539.154 us; speedup vs baseline: 1.3253x; 1.1563x over previous
//
#include <hip/hip_runtime.h>
#include <cstdint>
#include <cstddef>

#define NN 50000
#define EE 800000
#define CAP 64
#define EPS_BN 1e-5f

typedef short  s16x8 __attribute__((ext_vector_type(8)));
typedef ushort u16x8 __attribute__((ext_vector_type(8)));
typedef float  f32x4 __attribute__((ext_vector_type(4)));

#define MFMA16(a, b, c) __builtin_amdgcn_mfma_f32_16x16x32_bf16((a), (b), (c), 0, 0, 0)

__device__ inline ushort f2bf(float f){           // round-to-nearest-even fp32->bf16
  uint32_t u = __float_as_uint(f);
  uint32_t r = (u + 0x7FFFu + ((u >> 16) & 1u)) >> 16;
  return (ushort)r;
}
__device__ inline float bf2f(ushort u){ return __uint_as_float((uint32_t)u << 16); }

// ---------------- graph preprocessing ----------------

__global__ void k_outdeg(const int* __restrict__ row, int* __restrict__ outdeg){
  int e = blockIdx.x * blockDim.x + threadIdx.x;
  if (e < EE) atomicAdd(&outdeg[row[e]], 1);
}

__global__ void k_fill(const int* __restrict__ row, const int* __restrict__ col,
                       const int* __restrict__ outdeg,
                       int* __restrict__ incnt, int* __restrict__ bsrc,
                       float* __restrict__ bnorm){
  int e = blockIdx.x * blockDim.x + threadIdx.x;
  if (e >= EE) return;
  int r = row[e], c = col[e];
  int j = atomicAdd(&incnt[c], 1);
  if (j < CAP){
    bsrc[(size_t)c * CAP + j]  = r;
    bnorm[(size_t)c * CAP + j] = 1.0f / fmaxf((float)outdeg[r], 1.0f);
  }
}

// ---------------- fp32 -> bf16 bulk convert ----------------

__global__ void k_cvt(const float* __restrict__ src, ushort* __restrict__ dst, int n4){
  int i = blockIdx.x * blockDim.x + threadIdx.x;
  int stride = gridDim.x * blockDim.x;
  for (; i < n4; i += stride){
    float4 v = ((const float4*)src)[i];
    ushort4 u = {f2bf(v.x), f2bf(v.y), f2bf(v.z), f2bf(v.w)};
    ((ushort4*)dst)[i] = u;
  }
}

// ------- weight conversion: fp32 [K x NF] -> bf16 MFMA-fragment order -------
// dst[((ct*P + p)*2 + ks)*512 + lane*8 + j] = W[k][col]
//   col = ct*16 + (lane&15),  k = p*64 + ks*32 + (lane>>4)*8 + j
// so a wave's B-fragment load is one contiguous 1KB burst.
// mode: 0 = single src; 1 = k-split at splitVal (srcB rows); 2 = col-split.

struct FJob { const float* srcA; const float* srcB; ushort* dst;
              int NF; int NCT; int P; int mode; int splitVal; };
struct FJobs { FJob j[10]; };

__global__ void k_conv(FJobs J){
  FJob jb = J.j[blockIdx.x];
  int total = jb.NCT * jb.P * 1024;
  for (int idx = threadIdx.x + blockIdx.y * 256; idx < total; idx += 256 * gridDim.y){
    int j = idx & 7, lane = (idx >> 3) & 63, ks = (idx >> 9) & 1;
    int rest = idx >> 10;
    int p = rest % jb.P, ct = rest / jb.P;
    int col = ct * 16 + (lane & 15);
    int k   = p * 64 + ks * 32 + (lane >> 4) * 8 + j;
    const float* s = jb.srcA;
    int sc = col, sk = k;
    if (jb.mode == 1 && k   >= jb.splitVal){ s = jb.srcB; sk = k   - jb.splitVal; }
    if (jb.mode == 2 && col >= jb.splitVal){ s = jb.srcB; sc = col - jb.splitVal; }
    jb.dst[idx] = f2bf(s[(size_t)sk * jb.NF + sc]);
  }
}

// ---------------- aggregation (bf16 in/out): out[c] = sum_e w_e * hin[src_e] --------
// wave per node; 8 lanes x 16B per source row; 8 edges in flight per iter.

__global__ void __launch_bounds__(256) k_agg(const ushort* __restrict__ hin,
                                             ushort* __restrict__ out,
                                             const int* __restrict__ bsrc,
                                             const float* __restrict__ bnorm,
                                             const int* __restrict__ incnt,
                                             int use_norm){
  __shared__ int   sidx[4][CAP];
  __shared__ float swgt[4][CAP];
  int wib  = threadIdx.x >> 6;
  int lane = threadIdx.x & 63;
  int wid  = blockIdx.x * 4 + wib;
  bool valid = wid < NN;
  int cnt  = valid ? incnt[wid] : 0;
  int cntb = min(cnt, CAP);
  if (valid){
    int   si = (lane < cntb) ? bsrc[(size_t)wid * CAP + lane] : 0;
    float wv;
    if (use_norm) wv = (lane < cntb) ? bnorm[(size_t)wid * CAP + lane] : 0.f;
    else          wv = (lane < cntb) ? 1.0f / fmaxf((float)cnt, 1.f) : 0.f;
    sidx[wib][lane] = si;
    swgt[wib][lane] = wv;
  }
  __syncthreads();
  if (!valid) return;

  int g  = lane >> 3;     // edge slot within oct (0..7)
  int fl = lane & 7;      // 16B feature chunk (8 bf16)
  float accf[8] = {0,0,0,0,0,0,0,0};
  for (int e0 = 0; e0 < cntb; e0 += 8){
    int e = e0 + g;                       // <= 63 always
    int   s = sidx[wib][e];
    float w = swgt[wib][e];
    u16x8 v = *(const u16x8*)(hin + (size_t)s * 64 + fl * 8);
    #pragma unroll
    for (int j = 0; j < 8; ++j) accf[j] = fmaf(w, bf2f(v[j]), accf[j]);
  }
  #pragma unroll
  for (int m = 8; m < 64; m <<= 1){
    #pragma unroll
    for (int j = 0; j < 8; ++j) accf[j] += __shfl_xor(accf[j], m);
  }
  if (lane < 8){
    u16x8 o;
    #pragma unroll
    for (int j = 0; j < 8; ++j) o[j] = f2bf(accf[j]);
    *(u16x8*)(out + (size_t)wid * 64 + lane * 8) = o;
  }
}

// ---------------- direct-load MFMA GEMM (no LDS, no barriers) ----------------
// Wave handles 16 rows. A-frag: 16B global load from bf16 [N][64] row-major at
// row=rowbase+(lane&15), k=(lane>>4)*8. B-frag: contiguous 1KB chunk per
// (ct,p,ks) from fragment-ordered WB.  C/D: col=lane&15, row=(lane>>4)*4+reg.

template<int P, int NCT>
__device__ inline void gemm_direct(const ushort* const* pieces,
                                   const ushort* __restrict__ WB,
                                   int rowbase, f32x4* acc){
  int lane = threadIdx.x & 63;
  int q = lane >> 4, r16 = lane & 15;
  int ar = rowbase + r16; ar = (ar < NN) ? ar : (NN - 1);
  const ushort* wl = WB + lane * 8;
  #pragma unroll
  for (int p = 0; p < P; ++p){
    const ushort* src = pieces[p] + (size_t)ar * 64 + q * 8;
    #pragma unroll
    for (int ks = 0; ks < 2; ++ks){
      s16x8 a = *(const s16x8*)(src + ks * 32);
      #pragma unroll
      for (int ct = 0; ct < NCT; ++ct){
        s16x8 b = *(const s16x8*)(wl + (((ct * P + p) * 2 + ks) << 9));
        acc[ct] = MFMA16(a, b, acc[ct]);
      }
    }
  }
}

// ---- skip = x @ W_in + b_in  (bf16 out) ----
__global__ void __launch_bounds__(256) k_skip(const ushort* __restrict__ xb,
                                              const ushort* __restrict__ WT,
                                              const float* __restrict__ bias,
                                              ushort* __restrict__ outb){
  int lane = threadIdx.x & 63, wv = threadIdx.x >> 6, q = lane >> 4, r16 = lane & 15;
  int rowbase = blockIdx.x * 64 + wv * 16;
  const ushort* pieces[1] = {xb};
  f32x4 acc[4] = {};
  gemm_direct<1, 4>(pieces, WT, rowbase, acc);
  #pragma unroll
  for (int ct = 0; ct < 4; ++ct){
    int col = ct * 16 + r16;
    float b = bias[col];
    #pragma unroll
    for (int r = 0; r < 4; ++r){
      int row = rowbase + q * 4 + r;
      if (row < NN) outb[(size_t)row * 64 + col] = f2bf(acc[ct][r] + b);
    }
  }
}

// ---- sage layer: out = relu(bn([mean|h]@[Wl;Wr] + bl)) + h   (bf16 in/out) ----
__global__ void __launch_bounds__(256) k_sage_m(const ushort* __restrict__ meanb,
                                                const ushort* __restrict__ hb,
                                                const ushort* __restrict__ WT,
                                                const float* __restrict__ bl,
                                                const float* __restrict__ g,
                                                const float* __restrict__ be,
                                                const float* __restrict__ m_,
                                                const float* __restrict__ var_,
                                                ushort* __restrict__ houtb){
  int lane = threadIdx.x & 63, wv = threadIdx.x >> 6, q = lane >> 4, r16 = lane & 15;
  int rowbase = blockIdx.x * 64 + wv * 16;
  const ushort* pieces[2] = {meanb, hb};
  f32x4 acc[4] = {};
  gemm_direct<2, 4>(pieces, WT, rowbase, acc);
  #pragma unroll
  for (int ct = 0; ct < 4; ++ct){
    int col = ct * 16 + r16;
    float sc = g[col] * rsqrtf(var_[col] + EPS_BN);
    float sh = be[col] - m_[col] * sc;
    float bb = bl[col];
    #pragma unroll
    for (int r = 0; r < 4; ++r){
      int row = rowbase + q * 4 + r;
      if (row < NN){
        float t = (acc[ct][r] + bb) * sc + sh;
        float hv = bf2f(hb[(size_t)row * 64 + col]);
        houtb[(size_t)row * 64 + col] = f2bf(fmaxf(t, 0.f) + hv);
      }
    }
  }
}

// ---- YR: [h1..h4|skip|path](384) @ [vWl|vWr] -> Y, R(+vbl)   (bf16 out) ----
__global__ void __launch_bounds__(256) k_yr(const ushort* __restrict__ x0, const ushort* __restrict__ x1,
                                            const ushort* __restrict__ x2, const ushort* __restrict__ x3,
                                            const ushort* __restrict__ x4, const ushort* __restrict__ x5,
                                            const ushort* __restrict__ WT, const float* __restrict__ vbl,
                                            ushort* __restrict__ Y, ushort* __restrict__ R){
  int lane = threadIdx.x & 63, wv = threadIdx.x >> 6, q = lane >> 4, r16 = lane & 15;
  int rowbase = blockIdx.x * 64 + wv * 16;
  const ushort* pieces[6] = {x0, x1, x2, x3, x4, x5};
  f32x4 acc[8] = {};
  gemm_direct<6, 8>(pieces, WT, rowbase, acc);
  #pragma unroll
  for (int ct = 0; ct < 8; ++ct){
    int col = ct * 16 + r16;
    bool isR = col >= 64;
    int c2 = isR ? (col - 64) : col;
    float b = isR ? vbl[c2] : 0.f;
    ushort* dst = isR ? R : Y;
    #pragma unroll
    for (int r = 0; r < 4; ++r){
      int row = rowbase + q * 4 + r;
      if (row < NN) dst[(size_t)row * 64 + c2] = f2bf(acc[ct][r] + b);
    }
  }
}

// ---- mulv: v = relu(bn(Yagg+R)); [mu|lv] = v @ [Wmu|Wlv] + [bmu|blv] ----
__global__ void __launch_bounds__(256) k_mulv_m(const ushort* __restrict__ Yagg,
                                                const ushort* __restrict__ Rb,
                                                const float* __restrict__ vg,
                                                const float* __restrict__ vbe,
                                                const float* __restrict__ vm,
                                                const float* __restrict__ vvar,
                                                const ushort* __restrict__ WT,
                                                const float* __restrict__ bmu,
                                                const float* __restrict__ blv,
                                                float* __restrict__ muf, float* __restrict__ lvf,
                                                ushort* __restrict__ mub){
  __shared__ float ssc[64], ssh[64];
  int t = threadIdx.x;
  if (t < 64){
    float sc = vg[t] * rsqrtf(vvar[t] + EPS_BN);
    ssc[t] = sc; ssh[t] = vbe[t] - vm[t] * sc;
  }
  __syncthreads();
  int lane = t & 63, wv = t >> 6, q = lane >> 4, r16 = lane & 15;
  int rowbase = blockIdx.x * 64 + wv * 16;
  int ar = rowbase + r16; ar = (ar < NN) ? ar : (NN - 1);
  const ushort* wl = WT + lane * 8;
  f32x4 acc[8] = {};
  #pragma unroll
  for (int ks = 0; ks < 2; ++ks){
    int k0 = ks * 32 + q * 8;
    u16x8 y  = *(const u16x8*)(Yagg + (size_t)ar * 64 + k0);
    u16x8 rv = *(const u16x8*)(Rb   + (size_t)ar * 64 + k0);
    s16x8 a;
    #pragma unroll
    for (int j = 0; j < 8; ++j){
      float tv = (bf2f(y[j]) + bf2f(rv[j])) * ssc[k0 + j] + ssh[k0 + j];
      a[j] = (short)f2bf(fmaxf(tv, 0.f));
    }
    #pragma unroll
    for (int ct = 0; ct < 8; ++ct){
      s16x8 b = *(const s16x8*)(wl + (((ct * 1) * 2 + ks) << 9));
      acc[ct] = MFMA16(a, b, acc[ct]);
    }
  }
  #pragma unroll
  for (int ct = 0; ct < 8; ++ct){
    int col = ct * 16 + r16;
    bool isL = col >= 64;
    int c2 = isL ? (col - 64) : col;
    float bb = isL ? blv[c2] : bmu[c2];
    #pragma unroll
    for (int r = 0; r < 4; ++r){
      int row = rowbase + q * 4 + r;
      if (row < NN){
        float v = acc[ct][r] + bb;
        if (isL) lvf[(size_t)row * 64 + c2] = v;
        else { muf[(size_t)row * 64 + c2] = v; mub[(size_t)row * 64 + c2] = f2bf(v); }
      }
    }
  }
}

// ---- rank = relu(mu@rW1+rb1) @ rW2 + rb2 ----
__global__ void __launch_bounds__(256) k_rank_m(const ushort* __restrict__ mub,
                                                const ushort* __restrict__ WT,
                                                const float* __restrict__ rb1,
                                                const float* __restrict__ rW2,
                                                const float* __restrict__ rb2,
                                                float* __restrict__ rout){
  int lane = threadIdx.x & 63, wv = threadIdx.x >> 6, q = lane >> 4, r16 = lane & 15;
  int rowbase = blockIdx.x * 64 + wv * 16;
  const ushort* pieces[1] = {mub};
  f32x4 acc[4] = {};
  gemm_direct<1, 4>(pieces, WT, rowbase, acc);
  float val[4] = {0.f, 0.f, 0.f, 0.f};
  #pragma unroll
  for (int ct = 0; ct < 4; ++ct){
    int col = ct * 16 + r16;
    float b1 = rb1[col], w2 = rW2[col];
    #pragma unroll
    for (int r = 0; r < 4; ++r)
      val[r] += fmaxf(acc[ct][r] + b1, 0.f) * w2;
  }
  #pragma unroll
  for (int r = 0; r < 4; ++r){
    #pragma unroll
    for (int m = 1; m < 16; m <<= 1) val[r] += __shfl_xor(val[r], m);
  }
  if (r16 == 0){
    float b2 = rb2[0];
    #pragma unroll
    for (int r = 0; r < 4; ++r){
      int row = rowbase + q * 4 + r;
      if (row < NN) rout[row] = val[r] + b2;
    }
  }
}

// ---- reg stage 1: h1 = relu([stage1|z](384)@gW1[0:384] + gb1 + rank*gW1[384]) ----
__global__ void __launch_bounds__(256) k_reg1(const ushort* __restrict__ x0, const ushort* __restrict__ x1,
                                              const ushort* __restrict__ x2, const ushort* __restrict__ x3,
                                              const ushort* __restrict__ x4, const ushort* __restrict__ x5,
                                              const float* __restrict__ rank,
                                              const ushort* __restrict__ WT,
                                              const float* __restrict__ gW1,   // fp32, for row 384
                                              const float* __restrict__ gb1,
                                              ushort* __restrict__ h1b){
  int lane = threadIdx.x & 63, wv = threadIdx.x >> 6, q = lane >> 4, r16 = lane & 15;
  int rowbase = blockIdx.x * 64 + wv * 16;
  const ushort* pieces[6] = {x0, x1, x2, x3, x4, x5};
  f32x4 acc[4] = {};
  gemm_direct<6, 4>(pieces, WT, rowbase, acc);
  float rk[4];
  #pragma unroll
  for (int r = 0; r < 4; ++r){
    int row = rowbase + q * 4 + r;
    rk[r] = (row < NN) ? rank[row] : 0.f;
  }
  #pragma unroll
  for (int ct = 0; ct < 4; ++ct){
    int col = ct * 16 + r16;
    float b1 = gb1[col];
    float w384 = gW1[384 * 64 + col];
    #pragma unroll
    for (int r = 0; r < 4; ++r){
      int row = rowbase + q * 4 + r;
      if (row < NN)
        h1b[(size_t)row * 64 + col] = f2bf(fmaxf(acc[ct][r] + b1 + rk[r] * w384, 0.f));
    }
  }
}

// ---- reg tail: h2 = relu(h1@gW2+gb2); preds = h2@gW3 + gb3 ----
__global__ void __launch_bounds__(256) k_reg2(const ushort* __restrict__ h1b,
                                              const ushort* __restrict__ WT,
                                              const float* __restrict__ gb2,
                                              const float* __restrict__ gW3,
                                              const float* __restrict__ gb3,
                                              float* __restrict__ preds){
  int lane = threadIdx.x & 63, wv = threadIdx.x >> 6, q = lane >> 4, r16 = lane & 15;
  int rowbase = blockIdx.x * 64 + wv * 16;
  const ushort* pieces[1] = {h1b};
  f32x4 acc[2] = {};
  gemm_direct<1, 2>(pieces, WT, rowbase, acc);
  float val[4] = {0.f, 0.f, 0.f, 0.f};
  #pragma unroll
  for (int ct = 0; ct < 2; ++ct){
    int col = ct * 16 + r16;       // 0..31
    float b2 = gb2[col], w3 = gW3[col];
    #pragma unroll
    for (int r = 0; r < 4; ++r)
      val[r] += fmaxf(acc[ct][r] + b2, 0.f) * w3;
  }
  #pragma unroll
  for (int r = 0; r < 4; ++r){
    #pragma unroll
    for (int m = 1; m < 16; m <<= 1) val[r] += __shfl_xor(val[r], m);
  }
  if (r16 == 0){
    float b3 = gb3[0];
    #pragma unroll
    for (int r = 0; r < 4; ++r){
      int row = rowbase + q * 4 + r;
      if (row < NN) preds[row] = val[r] + b3;
    }
  }
}

// ---------------- launch ----------------

extern "C" void kernel_launch(void* const* d_in, const int* in_sizes, int n_in,
                              void* d_out, int out_size, void* d_ws, size_t ws_size,
                              hipStream_t stream){
  const float* x    = (const float*)d_in[0];
  const int*   eidx = (const int*)d_in[1];
  const int* row = eidx;
  const int* col = eidx + EE;
  const float* W_in = (const float*)d_in[2];
  const float* b_in = (const float*)d_in[3];
  const float* sWl  = (const float*)d_in[4];
  const float* sbl  = (const float*)d_in[5];
  const float* sWr  = (const float*)d_in[6];
  const float* bng  = (const float*)d_in[7];
  const float* bnb  = (const float*)d_in[8];
  const float* bnm  = (const float*)d_in[9];
  const float* bnv  = (const float*)d_in[10];
  const float* vWl  = (const float*)d_in[11];
  const float* vbl  = (const float*)d_in[12];
  const float* vWr  = (const float*)d_in[13];
  const float* vg   = (const float*)d_in[14];
  const float* vbe  = (const float*)d_in[15];
  const float* vm   = (const float*)d_in[16];
  const float* vvar = (const float*)d_in[17];
  const float* Wmu  = (const float*)d_in[18];
  const float* bmu  = (const float*)d_in[19];
  const float* Wlv  = (const float*)d_in[20];
  const float* blv  = (const float*)d_in[21];
  const float* rW1  = (const float*)d_in[22];
  const float* rb1  = (const float*)d_in[23];
  const float* rW2  = (const float*)d_in[24];
  const float* rb2  = (const float*)d_in[25];
  const float* gW1  = (const float*)d_in[26];
  const float* gb1  = (const float*)d_in[27];
  const float* gW2  = (const float*)d_in[28];
  const float* gb2  = (const float*)d_in[29];
  const float* gW3  = (const float*)d_in[30];
  const float* gb3  = (const float*)d_in[31];

  float* preds = (float*)d_out;
  float* rank  = preds + NN;
  float* mu    = rank + NN;
  float* lv    = mu + (size_t)NN * 64;

  char* w = (char*)d_ws;
  auto alloc = [&](size_t bytes) -> char* {
    char* p = w; w += (bytes + 255) & ~(size_t)255; return p;
  };
  int*   outdeg = (int*)alloc((size_t)NN * 4);
  int*   incnt  = (int*)alloc((size_t)NN * 4);
  int*   bsrc   = (int*)alloc((size_t)NN * CAP * 4);
  float* bnorm  = (float*)alloc((size_t)NN * CAP * 4);
  const size_t FB = (size_t)NN * 64 * 2;           // bf16 feature buffer
  ushort* xb    = (ushort*)alloc(FB);
  ushort* skipb = (ushort*)alloc(FB);
  ushort* hb[4];
  for (int i = 0; i < 4; ++i) hb[i] = (ushort*)alloc(FB);
  ushort* meanb = (ushort*)alloc(FB);
  ushort* pa    = (ushort*)alloc(FB);              // path scratch; reused as h1buf
  ushort* pb    = (ushort*)alloc(FB);
  ushort* Yb    = (ushort*)alloc(FB);
  ushort* Rb    = (ushort*)alloc(FB);
  ushort* mub   = (ushort*)alloc(FB);
  ushort* skipW = (ushort*)alloc(4 * 1024 * 2);        // NCT4 P1
  ushort* sageW = (ushort*)alloc(4 * 8 * 1024 * 2);    // 4 layers x NCT4 P2
  ushort* yrW   = (ushort*)alloc(48 * 1024 * 2);       // NCT8 P6
  ushort* mulvW = (ushort*)alloc(8 * 1024 * 2);        // NCT8 P1
  ushort* rankW = (ushort*)alloc(4 * 1024 * 2);        // NCT4 P1
  ushort* regW1 = (ushort*)alloc(24 * 1024 * 2);       // NCT4 P6
  ushort* regW2 = (ushort*)alloc(2 * 1024 * 2);        // NCT2 P1

  hipMemsetAsync(outdeg, 0, (size_t)NN * 4, stream);
  hipMemsetAsync(incnt,  0, (size_t)NN * 4, stream);

  const int EB = (EE + 255) / 256;
  k_outdeg<<<EB, 256, 0, stream>>>(row, outdeg);
  k_fill  <<<EB, 256, 0, stream>>>(row, col, outdeg, incnt, bsrc, bnorm);

  // weight conversions to fragment order (10 jobs)
  FJobs J;
  auto job = [&](int i, const float* sA, const float* sB, ushort* d,
                 int NF, int NCT, int P, int mode, int splitVal){
    J.j[i] = {sA, sB, d, NF, NCT, P, mode, splitVal};
  };
  job(0, W_in, nullptr, skipW, 64, 4, 1, 0, 0);
  for (int i = 0; i < 4; ++i)
    job(1 + i, sWl + i * 4096, sWr + i * 4096, sageW + i * 8192, 64, 4, 2, 1, 64);
  job(5, vWl, vWr, yrW,   64, 8, 6, 2, 64);
  job(6, Wmu, Wlv, mulvW, 64, 8, 1, 2, 64);
  job(7, rW1, nullptr, rankW, 64, 4, 1, 0, 0);
  job(8, gW1, nullptr, regW1, 64, 4, 6, 0, 0);
  job(9, gW2, nullptr, regW2, 32, 2, 1, 0, 0);
  k_conv<<<dim3(10, 8), 256, 0, stream>>>(J);

  k_cvt<<<1024, 256, 0, stream>>>(x, xb, NN * 64 / 4);

  const int GB = (NN + 63) / 64;   // 782 row-tile blocks
  k_skip<<<GB, 256, 0, stream>>>(xb, skipW, b_in, skipb);

  const int AGG_B = (NN + 3) / 4;
  const ushort* hprev = xb;
  for (int i = 0; i < 4; ++i){
    k_agg<<<AGG_B, 256, 0, stream>>>(hprev, meanb, bsrc, bnorm, incnt, 0);
    k_sage_m<<<GB, 256, 0, stream>>>(meanb, hprev, sageW + i * 8192, sbl + i * 64,
                                     bng + i * 64, bnb + i * 64, bnm + i * 64, bnv + i * 64, hb[i]);
    hprev = hb[i];
  }

  k_agg<<<AGG_B, 256, 0, stream>>>(hb[3], pa, bsrc, bnorm, incnt, 1);
  k_agg<<<AGG_B, 256, 0, stream>>>(pa, pb, bsrc, bnorm, incnt, 1);
  k_agg<<<AGG_B, 256, 0, stream>>>(pb, pa, bsrc, bnorm, incnt, 1);
  k_agg<<<AGG_B, 256, 0, stream>>>(pa, pb, bsrc, bnorm, incnt, 1);
  // path_out = pb

  k_yr<<<GB, 256, 0, stream>>>(hb[0], hb[1], hb[2], hb[3], skipb, pb, yrW, vbl, Yb, Rb);
  k_agg<<<AGG_B, 256, 0, stream>>>(Yb, meanb, bsrc, bnorm, incnt, 0);
  k_mulv_m<<<GB, 256, 0, stream>>>(meanb, Rb, vg, vbe, vm, vvar, mulvW, bmu, blv, mu, lv, mub);
  k_rank_m<<<GB, 256, 0, stream>>>(mub, rankW, rb1, rW2, rb2, rank);
  k_reg1<<<GB, 256, 0, stream>>>(hb[0], hb[1], hb[2], hb[3], skipb, mub, rank,
                                 regW1, gW1, gb1, pa);
  k_reg2<<<GB, 256, 0, stream>>>(pa, regW2, gb2, gW3, gb3, preds);
}